// Round 16
// baseline (180.568 us; speedup 1.0000x reference)
//
#include <hip/hip_runtime.h>
#include <hip/hip_bf16.h>

typedef __attribute__((ext_vector_type(4))) float  f32x4;
typedef __attribute__((ext_vector_type(8))) _Float16 h16x8;
typedef __attribute__((ext_vector_type(2))) __fp16 fp16x2;
typedef const __attribute__((address_space(1))) unsigned int guint;
typedef __attribute__((address_space(3))) unsigned int luint;

#define EMB 128
#define NSEQ 4096
#define NB 8
#define SCALE 0.08838834764831845f   // 1/sqrt(128)
#define QSC   (0.08838834764831845f * 1.44269504f)   // SCALE * log2(e)
#define NT    (NSEQ / 64)            // 64 kv-tiles of 64

#if __has_builtin(__builtin_amdgcn_exp2f)
#define EXP2(x) __builtin_amdgcn_exp2f(x)
#else
#define EXP2(x) exp2f(x)
#endif

// ---------------- prep: hi/lo split transposed weights ----------------
__global__ void prep_w(const float* __restrict__ wq, const float* __restrict__ wk,
                       const float* __restrict__ wv, _Float16* __restrict__ whiT,
                       _Float16* __restrict__ wloT) {
    int idx = blockIdx.x * 256 + threadIdx.x;          // 3*128*128 = 49152
    if (idx >= 3 * EMB * EMB) return;
    int widx = idx >> 14;
    int rem  = idx & 16383;
    int d = rem >> 7;
    int e = rem & 127;
    const float* w = (widx == 0) ? wq : (widx == 1) ? wk : wv;
    float v = w[d * 128 + e];
    _Float16 hi = (_Float16)v;
    _Float16 lo = (_Float16)(v - (float)hi);
    whiT[(size_t)widx * 16384 + (size_t)e * 128 + d] = hi;
    wloT[(size_t)widx * 16384 + (size_t)e * 128 + d] = lo;
}

// ---------------- QKV projection ----------------
// q: [tok][128] f16 = (Q - c_q)*QSC ; aq = c_q*128*QSC ; ck = c_k.
// K and V written as PRE-PERMUTED + PRE-XOR-SWIZZLED 16 KB tile images
// (KVBLK=64; the exact LDS images flash stages via global_load_lds):
//   kimg[b][t] (64 slots x 256B): slot = (2*(kv>>5)+((kv>>2)&1))*16
//                + (((kv>>3)&3)<<2) + (kv&3); byte = slot*256 + ((2e)^((slot&15)<<4))
//   vimg[b][t] (128 e-rows x 128B): byte = e*128 + ((2kv) ^ ((e&7)<<4))
__global__ __launch_bounds__(256) void qkv_proj(const float* __restrict__ x,
                                                const _Float16* __restrict__ whiT,
                                                const _Float16* __restrict__ wloT,
                                                _Float16* __restrict__ q,
                                                char* __restrict__ kimg,
                                                char* __restrict__ vimg,
                                                float* __restrict__ aq,
                                                float* __restrict__ ck) {
    const int widx = blockIdx.x >> 9;          // 0,1,2
    const int blk  = blockIdx.x & 511;
    const int lane = threadIdx.x & 63;
    const int wave = threadIdx.x >> 6;
    const int g    = lane >> 4;
    const int lr   = lane & 15;
    const int rb   = blk * 64 + wave * 16;

    h16x8 xhi[4], xlo[4];
    {
        const float* xrow = x + (size_t)(rb + lr) * EMB;
        #pragma unroll
        for (int kc = 0; kc < 4; ++kc) {
            const float* p = xrow + kc * 32 + g * 8;
            h16x8 ah, al;
            #pragma unroll
            for (int j = 0; j < 8; ++j) {
                float v = p[j];
                _Float16 h = (_Float16)v;
                ah[j] = h;
                al[j] = (_Float16)(v - (float)h);
            }
            xhi[kc] = ah;
            if (widx < 2) xlo[kc] = al;
        }
    }

    const int b  = rb >> 12;
    const int n0 = rb & 4095;

    f32x4 acc[8];
    #pragma unroll
    for (int ct = 0; ct < 8; ++ct) acc[ct] = (f32x4){0.f, 0.f, 0.f, 0.f};

    const _Float16* wh = whiT + (size_t)widx * 16384;
    const _Float16* wl = wloT + (size_t)widx * 16384;
    #pragma unroll
    for (int kc = 0; kc < 4; ++kc) {
        #pragma unroll
        for (int ct = 0; ct < 8; ++ct) {
            size_t off = (size_t)(ct * 16 + lr) * 128 + kc * 32 + g * 8;
            h16x8 bh = *(const h16x8*)(wh + off);
            acc[ct] = __builtin_amdgcn_mfma_f32_16x16x32_f16(xhi[kc], bh, acc[ct], 0, 0, 0);
            if (widx < 2) {
                h16x8 bl = *(const h16x8*)(wl + off);
                acc[ct] = __builtin_amdgcn_mfma_f32_16x16x32_f16(xlo[kc], bh, acc[ct], 0, 0, 0);
                acc[ct] = __builtin_amdgcn_mfma_f32_16x16x32_f16(xhi[kc], bl, acc[ct], 0, 0, 0);
            }
        }
    }

    if (widx < 2) {
        float c[4];
        #pragma unroll
        for (int r = 0; r < 4; ++r) {
            float rs = 0.f;
            #pragma unroll
            for (int ct = 0; ct < 8; ++ct) rs += acc[ct][r];
            #pragma unroll
            for (int off = 8; off; off >>= 1) rs += __shfl_xor(rs, off);
            c[r] = rs * (1.0f / 128.0f);
        }
        if (widx == 0) {
            #pragma unroll
            for (int ct = 0; ct < 8; ++ct)
                #pragma unroll
                for (int r = 0; r < 4; ++r) {
                    size_t row = rb + g * 4 + r;
                    q[row * 128 + ct * 16 + lr] = (_Float16)((acc[ct][r] - c[r]) * QSC);
                }
            if (lr == 0) {
                #pragma unroll
                for (int r = 0; r < 4; ++r) aq[rb + g * 4 + r] = c[r] * 128.0f * QSC;
            }
        } else {
            #pragma unroll
            for (int ct = 0; ct < 8; ++ct)
                #pragma unroll
                for (int r = 0; r < 4; ++r) {
                    int nn  = n0 + g * 4 + r;
                    int tt  = nn >> 6, r64 = nn & 63;
                    int slot = ((r64 >> 5) * 2 + ((r64 >> 2) & 1)) * 16
                             + (((r64 >> 3) & 3) << 2) + (r64 & 3);
                    int e = ct * 16 + lr;
                    size_t byte = ((size_t)(b * 64 + tt) << 14) + slot * 256
                                + ((2 * e) ^ ((slot & 15) << 4));
                    *(_Float16*)(kimg + byte) = (_Float16)(acc[ct][r] - c[r]);
                }
            if (lr == 0) {
                #pragma unroll
                for (int r = 0; r < 4; ++r) ck[rb + g * 4 + r] = c[r];
            }
        }
    } else {
        #pragma unroll
        for (int ct = 0; ct < 8; ++ct)
            #pragma unroll
            for (int r = 0; r < 4; ++r) {
                int e  = ct * 16 + lr;
                int nn = n0 + g * 4 + r;
                int tt = nn >> 6, kv = nn & 63;
                size_t byte = ((size_t)(b * 64 + tt) << 14) + e * 128
                            + ((2 * kv) ^ ((e & 7) << 4));
                *(_Float16*)(vimg + byte) = (_Float16)acc[ct][r];
            }
    }
}

// ---------------- flash attention: 8-wave blocks, split-KV xN, DMA staging ----------------
// 512-thread blocks (8 waves), 256 q-rows/block, KVBLK=64 (r12's per-tile
// economics unchanged). Grid = 128*nsplit blocks; nsplit=4 -> 2 blocks/CU
// resident (LDS 64KB each) = 16 waves/CU = 4 waves/SIMD — 2x r12's TLP.
// Each 32 KB stage now feeds 8 waves (staging traffic halves).
// Lane (g,lr) owns P[q=lr][kv] per the permuted K slots -> PV A-frag direct.
__global__ __launch_bounds__(512, 3) void flash(const _Float16* __restrict__ q,
                                                const char* __restrict__ kimg,
                                                const char* __restrict__ vimg,
                                                const float* __restrict__ aq,
                                                const float* __restrict__ ck,
                                                float* __restrict__ O0,      // = d_out
                                                float* __restrict__ Oext,    // nsplit-1 partials
                                                float* __restrict__ mArr,    // nsplit x 32768
                                                float* __restrict__ lArr,    // nsplit x 32768
                                                int nsplit, int cnt) {
    __shared__ __align__(16) char KsB[2][16384];   // 64 slots x 256 B (swizzled image)
    __shared__ __align__(16) char VsB[2][16384];   // 128 rows x 128 B (swizzled image)

    // bijective XCD swizzle; grid = 128*nsplit (multiple of 8)
    const int nblk = 128 * nsplit;
    const int bp   = blockIdx.x;
    const int bid  = (bp & 7) * (nblk >> 3) + (bp >> 3);

    const int lane = threadIdx.x & 63;
    const int wave = threadIdx.x >> 6;     // 0..7
    const int g    = lane >> 4;
    const int lr   = lane & 15;
    const int perb = 16 * nsplit;          // blocks per batch
    const int b    = bid / perb;
    const int rem  = bid % perb;
    const int qt   = rem / nsplit;         // 0..15 (256-row q-tile)
    const int sp   = rem % nsplit;
    const int t0   = sp * cnt;
    const size_t baseA = (size_t)b * NSEQ + qt * 256 + wave * 32;   // rows A: +0..15
    const size_t baseB = baseA + 16;                                // rows B: +16..31

    float* __restrict__ Opart = (sp == 0) ? O0 : Oext + (size_t)(sp - 1) * NB * NSEQ * EMB;
    float* __restrict__ mOut  = mArr + (size_t)sp * (NB * NSEQ);
    float* __restrict__ lOut  = lArr + (size_t)sp * (NB * NSEQ);

    const char* kimg_b = kimg + ((size_t)b << 20);
    const char* vimg_b = vimg + ((size_t)b << 20);
    const float* ckb   = ck + (size_t)b * NSEQ;

    // Q fragments (QSC folded); per-lane softmax rows are qA = lr, qB = lr+16
    h16x8 qfA[4], qfB[4];
    #pragma unroll
    for (int kc = 0; kc < 4; ++kc) {
        qfA[kc] = *(const h16x8*)(q + (baseA + lr) * 128 + kc * 32 + g * 8);
        qfB[kc] = *(const h16x8*)(q + (baseB + lr) * 128 + kc * 32 + g * 8);
    }
    const float aqvA = aq[baseA + lr];
    const float aqvB = aq[baseB + lr];

    // DMA staging: per wave, 2 KB of K + 2 KB of V, linear (lane x 16 B)
    auto stage = [&](int tile, int buf) {
        const char* ks = kimg_b + ((size_t)tile << 14) + wave * 2048 + lane * 16;
        const char* vs = vimg_b + ((size_t)tile << 14) + wave * 2048 + lane * 16;
        char* kd = (char*)KsB[buf] + wave * 2048;
        char* vd = (char*)VsB[buf] + wave * 2048;
        #pragma unroll
        for (int i = 0; i < 2; ++i) {
            __builtin_amdgcn_global_load_lds((guint*)(ks + i * 1024), (luint*)(kd + i * 1024), 16, 0, 0);
            __builtin_amdgcn_global_load_lds((guint*)(vs + i * 1024), (luint*)(vd + i * 1024), 16, 0, 0);
        }
    };

    stage(t0, 0);
    __syncthreads();

    f32x4 oA[8], oB[8];
    #pragma unroll
    for (int ct = 0; ct < 8; ++ct) {
        oA[ct] = (f32x4){0.f, 0.f, 0.f, 0.f};
        oB[ct] = (f32x4){0.f, 0.f, 0.f, 0.f};
    }
    float mA = -1e30f, mB = -1e30f;
    float lA = 0.f, lB = 0.f;

    int cur = 0;
    for (int t = t0; t < t0 + cnt; ++t) {
        // (1) DMA-prefetch next tile (fire-and-forget; barrier drains it)
        int tn = (t + 1 < t0 + cnt) ? t + 1 : t;
        stage(tn, cur ^ 1);

        // (2) rank-1 coefficients, permuted to slot ownership
        f32x4 ckt[4];
        #pragma unroll
        for (int ct = 0; ct < 4; ++ct)
            ckt[ct] = *(const f32x4*)(ckb + t * 64 + (ct >> 1) * 32 + (ct & 1) * 4 + g * 8);

        // (3) S^T = mfma(K, Q) for BOTH q-sets; each kb read feeds 2 MFMAs
        const char* Kb = KsB[cur];
        f32x4 sA[4], sB[4];
        __builtin_amdgcn_s_setprio(1);
        #pragma unroll
        for (int ct = 0; ct < 4; ++ct) {
            f32x4 aA = (f32x4){0.f, 0.f, 0.f, 0.f};
            f32x4 aB = (f32x4){0.f, 0.f, 0.f, 0.f};
            #pragma unroll
            for (int kc = 0; kc < 4; ++kc) {
                h16x8 kb = *(const h16x8*)(Kb + (ct * 16 + lr) * 256 + ((kc * 64 + g * 16) ^ (lr << 4)));
                aA = __builtin_amdgcn_mfma_f32_16x16x32_f16(kb, qfA[kc], aA, 0, 0, 0);
                aB = __builtin_amdgcn_mfma_f32_16x16x32_f16(kb, qfB[kc], aB, 0, 0, 0);
            }
            #pragma unroll
            for (int r = 0; r < 4; ++r) {
                aA[r] += aqvA * ckt[ct][r];
                aB[r] += aqvB * ckt[ct][r];
            }
            sA[ct] = aA;
            sB[ct] = aB;
        }
        __builtin_amdgcn_s_setprio(0);

        // (4) per-lane softmax (log2 domain, defer-max, deferred l, raw v_exp)
        float tmA = sA[0][0], tmB = sB[0][0];
        #pragma unroll
        for (int ct = 0; ct < 4; ++ct)
            #pragma unroll
            for (int r = 0; r < 4; ++r) {
                tmA = fmaxf(tmA, sA[ct][r]);
                tmB = fmaxf(tmB, sB[ct][r]);
            }
        tmA = fmaxf(tmA, __shfl_xor(tmA, 16));
        tmA = fmaxf(tmA, __shfl_xor(tmA, 32));
        tmB = fmaxf(tmB, __shfl_xor(tmB, 16));
        tmB = fmaxf(tmB, __shfl_xor(tmB, 32));
        if (__any((tmA > mA + 11.544f) || (tmB > mB + 11.544f))) {
            float mnA = fmaxf(mA, tmA), mnB = fmaxf(mB, tmB);
            float scA = EXP2(mA - mnA), scB = EXP2(mB - mnB);
            mA = mnA; mB = mnB;
            lA *= scA; lB *= scB;
            float osA[4], osB[4];
            #pragma unroll
            for (int r = 0; r < 4; ++r) {
                osA[r] = __shfl(scA, (lane & 48) | (g * 4 + r));
                osB[r] = __shfl(scB, (lane & 48) | (g * 4 + r));
            }
            #pragma unroll
            for (int ct = 0; ct < 8; ++ct)
                #pragma unroll
                for (int r = 0; r < 4; ++r) {
                    oA[ct][r] *= osA[r];
                    oB[ct][r] *= osB[r];
                }
        }
        #pragma unroll
        for (int ct = 0; ct < 4; ++ct)
            #pragma unroll
            for (int r = 0; r < 4; ++r) {
                float pA = EXP2(sA[ct][r] - mA);
                float pB = EXP2(sB[ct][r] - mB);
                sA[ct][r] = pA; sB[ct][r] = pB;
                lA += pA; lB += pB;
            }

        // (5) pack P into PV A-fragments: 4 cvt_pkrtz ARE the 4 regs of h16x8
        union Pk { fp16x2 h2[4]; h16x8 v8; };
        h16x8 paA[2], paB[2];
        #pragma unroll
        for (int w = 0; w < 2; ++w) {
            Pk a, bk;
            a.h2[0]  = __builtin_amdgcn_cvt_pkrtz(sA[2 * w][0], sA[2 * w][1]);
            a.h2[1]  = __builtin_amdgcn_cvt_pkrtz(sA[2 * w][2], sA[2 * w][3]);
            a.h2[2]  = __builtin_amdgcn_cvt_pkrtz(sA[2 * w + 1][0], sA[2 * w + 1][1]);
            a.h2[3]  = __builtin_amdgcn_cvt_pkrtz(sA[2 * w + 1][2], sA[2 * w + 1][3]);
            bk.h2[0] = __builtin_amdgcn_cvt_pkrtz(sB[2 * w][0], sB[2 * w][1]);
            bk.h2[1] = __builtin_amdgcn_cvt_pkrtz(sB[2 * w][2], sB[2 * w][3]);
            bk.h2[2] = __builtin_amdgcn_cvt_pkrtz(sB[2 * w + 1][0], sB[2 * w + 1][1]);
            bk.h2[3] = __builtin_amdgcn_cvt_pkrtz(sB[2 * w + 1][2], sB[2 * w + 1][3]);
            paA[w] = a.v8;
            paB[w] = bk.v8;
        }

        // (6) O += P V — each vb read feeds 2 MFMAs
        const char* Vb = VsB[cur];
        __builtin_amdgcn_s_setprio(1);
        #pragma unroll
        for (int ct = 0; ct < 8; ++ct) {
            #pragma unroll
            for (int w = 0; w < 2; ++w) {
                h16x8 vb = *(const h16x8*)(Vb + (ct * 16 + lr) * 128 + ((w * 64 + g * 16) ^ ((lr & 7) << 4)));
                oA[ct] = __builtin_amdgcn_mfma_f32_16x16x32_f16(paA[w], vb, oA[ct], 0, 0, 0);
                oB[ct] = __builtin_amdgcn_mfma_f32_16x16x32_f16(paB[w], vb, oB[ct], 0, 0, 0);
            }
        }
        __builtin_amdgcn_s_setprio(0);

        // (7) barrier drains the DMA -> next tile resident
        __syncthreads();
        cur ^= 1;
    }

    // epilogue: finish row sums; write UNNORMALIZED partials + (m,l) per row
    lA += __shfl_xor(lA, 16);
    lA += __shfl_xor(lA, 32);
    lB += __shfl_xor(lB, 16);
    lB += __shfl_xor(lB, 32);
    if (lane < 16) {
        mOut[baseA + lr] = mA;  lOut[baseA + lr] = lA;
        mOut[baseB + lr] = mB;  lOut[baseB + lr] = lB;
    }
    #pragma unroll
    for (int ct = 0; ct < 8; ++ct)
        #pragma unroll
        for (int r = 0; r < 4; ++r) {
            size_t rowA = baseA + g * 4 + r;
            size_t rowB = baseB + g * 4 + r;
            Opart[rowA * EMB + ct * 16 + lr] = oA[ct][r];
            Opart[rowB * EMB + ct * 16 + lr] = oB[ct][r];
        }
}

// ---------------- merge the nsplit kv-partials ----------------
// out = sum_p O_p * w_p / sum_p l_p * w_p, w_p = exp2(m_p - max_p m_p).
// O_0 lives in d_out (in-place: each thread reads its own bytes then writes).
__global__ __launch_bounds__(256) void merge_n(const float* __restrict__ Oext,
                                               const float* __restrict__ mArr,
                                               const float* __restrict__ lArr,
                                               float* __restrict__ out, int nsplit) {
    int gid = blockIdx.x * 256 + threadIdx.x;    // 32768 rows x 16 threads
    int row = gid >> 4;
    int c0  = (gid & 15) * 8;
    float M = mArr[row];
    for (int p = 1; p < nsplit; ++p) M = fmaxf(M, mArr[p * (NB * NSEQ) + row]);
    f32x4 a0 = (f32x4){0.f, 0.f, 0.f, 0.f}, a1 = a0;
    float wsum = 0.f;
    for (int p = 0; p < nsplit; ++p) {
        float wp = EXP2(mArr[p * (NB * NSEQ) + row] - M);
        wsum += lArr[p * (NB * NSEQ) + row] * wp;
        const float* src = (p == 0) ? (out + (size_t)row * EMB + c0)
                                    : (Oext + (size_t)(p - 1) * NB * NSEQ * EMB
                                       + (size_t)row * EMB + c0);
        a0 += *(const f32x4*)src * wp;
        a1 += *(const f32x4*)(src + 4) * wp;
    }
    float inv = 1.0f / wsum;
    float* p0 = out + (size_t)row * EMB + c0;
    *(f32x4*)p0       = a0 * inv;
    *(f32x4*)(p0 + 4) = a1 * inv;
}

extern "C" void kernel_launch(void* const* d_in, const int* in_sizes, int n_in,
                              void* d_out, int out_size, void* d_ws, size_t ws_size,
                              hipStream_t stream) {
    const float* x  = (const float*)d_in[0];
    const float* wq = (const float*)d_in[1];
    const float* wk = (const float*)d_in[2];
    const float* wv = (const float*)d_in[3];

    char* ws = (char*)d_ws;
    _Float16* q    = (_Float16*)(ws);                          // 8 MB
    char*     kimg = (char*)    (ws + 8388608);                // 8 MB (tile images)
    char*     vimg = (char*)    (ws + 16777216);               // 8 MB (tile images)
    float*    aq   = (float*)   (ws + 25165824);               // 128 KB
    float*    ck   = (float*)   (ws + 25296896);               // 128 KB
    _Float16* whiT = (_Float16*)(ws + 25427968);               // 96 KB
    _Float16* wloT = (_Float16*)(ws + 25526272);               // 96 KB

    const size_t PART = 25690112;                      // partials base
    const size_t OSZ  = (size_t)NB * NSEQ * EMB * 4;   // 16 MB per partial
    const size_t MLSZ = (size_t)NB * NSEQ * 4;         // 128 KB per m/l array

    // nsplit=4 needs 3 extra partials + 8 m/l arrays; fall back to 2 if ws is small
    size_t need4 = PART + 3 * OSZ + 8 * MLSZ;
    int nsplit = (ws_size >= need4) ? 4 : 2;
    int cnt = NT / nsplit;

    float* Oext = (float*)(ws + PART);
    float* mArr = (float*)(ws + PART + (size_t)(nsplit - 1) * OSZ);
    float* lArr = mArr + (size_t)nsplit * (NB * NSEQ);

    prep_w<<<192, 256, 0, stream>>>(wq, wk, wv, whiT, wloT);
    qkv_proj<<<1536, 256, 0, stream>>>(x, whiT, wloT, q, kimg, vimg, aq, ck);
    flash<<<128 * nsplit, 512, 0, stream>>>(q, kimg, vimg, aq, ck,
                                            (float*)d_out, Oext, mArr, lArr, nsplit, cnt);
    merge_n<<<2048, 256, 0, stream>>>(Oext, mArr, lArr, (float*)d_out, nsplit);
}

// Round 17
// 139.783 us; speedup vs baseline: 1.2918x; 1.2918x over previous
//
#include <hip/hip_runtime.h>
#include <hip/hip_bf16.h>

typedef __attribute__((ext_vector_type(4))) float  f32x4;
typedef __attribute__((ext_vector_type(8))) _Float16 h16x8;
typedef __attribute__((ext_vector_type(2))) __fp16 fp16x2;
typedef const __attribute__((address_space(1))) unsigned int guint;
typedef __attribute__((address_space(3))) unsigned int luint;

#define EMB 128
#define NSEQ 4096
#define NB 8
#define SCALE 0.08838834764831845f   // 1/sqrt(128)
#define QSC   (0.08838834764831845f * 1.44269504f)   // SCALE * log2(e)
#define NT    (NSEQ / 64)

#if __has_builtin(__builtin_amdgcn_exp2f)
#define EXP2(x) __builtin_amdgcn_exp2f(x)
#else
#define EXP2(x) exp2f(x)
#endif

// ---------------- prep: hi/lo split transposed weights ----------------
__global__ void prep_w(const float* __restrict__ wq, const float* __restrict__ wk,
                       const float* __restrict__ wv, _Float16* __restrict__ whiT,
                       _Float16* __restrict__ wloT) {
    int idx = blockIdx.x * 256 + threadIdx.x;          // 3*128*128 = 49152
    if (idx >= 3 * EMB * EMB) return;
    int widx = idx >> 14;
    int rem  = idx & 16383;
    int d = rem >> 7;
    int e = rem & 127;
    const float* w = (widx == 0) ? wq : (widx == 1) ? wk : wv;
    float v = w[d * 128 + e];
    _Float16 hi = (_Float16)v;
    _Float16 lo = (_Float16)(v - (float)hi);
    whiT[(size_t)widx * 16384 + (size_t)e * 128 + d] = hi;
    wloT[(size_t)widx * 16384 + (size_t)e * 128 + d] = lo;
}

// ---------------- QKV projection ----------------
// Same math as r12 (hi/lo MFMA, mean-centering, pre-swizzled kimg/vimg), but
// all global output now goes through an LDS tile so stores are 16B coalesced
// (was 96 scalar 2B stores/thread). Image formulas group into 16B chunks:
// chunk j of a row lands at (16j ^ c), c = swizzle (multiple of 16).
// Block blk covers exactly kv-tile blk: tilebase = blk<<14.
__global__ __launch_bounds__(256) void qkv_proj(const float* __restrict__ x,
                                                const _Float16* __restrict__ whiT,
                                                const _Float16* __restrict__ wloT,
                                                _Float16* __restrict__ q,
                                                char* __restrict__ kimg,
                                                char* __restrict__ vimg,
                                                float* __restrict__ aq,
                                                float* __restrict__ ck) {
    __shared__ __align__(16) char TB[18432];   // 64x136 f16 (q/k) or 128x72 f16 (v)
    const int widx = blockIdx.x >> 9;          // 0,1,2
    const int blk  = blockIdx.x & 511;
    const int lane = threadIdx.x & 63;
    const int wave = threadIdx.x >> 6;
    const int g    = lane >> 4;
    const int lr   = lane & 15;
    const int rb   = blk * 64 + wave * 16;
    const int tok  = wave * 16 + g * 4;        // token within block (+r)

    h16x8 xhi[4], xlo[4];
    {
        const float* xrow = x + (size_t)(rb + lr) * EMB;
        #pragma unroll
        for (int kc = 0; kc < 4; ++kc) {
            const float* p = xrow + kc * 32 + g * 8;
            h16x8 ah, al;
            #pragma unroll
            for (int j = 0; j < 8; ++j) {
                float v = p[j];
                _Float16 h = (_Float16)v;
                ah[j] = h;
                al[j] = (_Float16)(v - (float)h);
            }
            xhi[kc] = ah;
            if (widx < 2) xlo[kc] = al;
        }
    }

    f32x4 acc[8];
    #pragma unroll
    for (int ct = 0; ct < 8; ++ct) acc[ct] = (f32x4){0.f, 0.f, 0.f, 0.f};

    const _Float16* wh = whiT + (size_t)widx * 16384;
    const _Float16* wl = wloT + (size_t)widx * 16384;
    #pragma unroll
    for (int kc = 0; kc < 4; ++kc) {
        #pragma unroll
        for (int ct = 0; ct < 8; ++ct) {
            size_t off = (size_t)(ct * 16 + lr) * 128 + kc * 32 + g * 8;
            h16x8 bh = *(const h16x8*)(wh + off);
            acc[ct] = __builtin_amdgcn_mfma_f32_16x16x32_f16(xhi[kc], bh, acc[ct], 0, 0, 0);
            if (widx < 2) {
                h16x8 bl = *(const h16x8*)(wl + off);
                acc[ct] = __builtin_amdgcn_mfma_f32_16x16x32_f16(xlo[kc], bh, acc[ct], 0, 0, 0);
                acc[ct] = __builtin_amdgcn_mfma_f32_16x16x32_f16(xhi[kc], bl, acc[ct], 0, 0, 0);
            }
        }
    }

    _Float16* T = (_Float16*)TB;
    if (widx < 2) {
        float c[4];
        #pragma unroll
        for (int r = 0; r < 4; ++r) {
            float rs = 0.f;
            #pragma unroll
            for (int ct = 0; ct < 8; ++ct) rs += acc[ct][r];
            #pragma unroll
            for (int off = 8; off; off >>= 1) rs += __shfl_xor(rs, off);
            c[r] = rs * (1.0f / 128.0f);
        }
        if (widx == 0) {
            #pragma unroll
            for (int ct = 0; ct < 8; ++ct)
                #pragma unroll
                for (int r = 0; r < 4; ++r)
                    T[(tok + r) * 136 + ct * 16 + lr] = (_Float16)((acc[ct][r] - c[r]) * QSC);
            if (lr == 0) {
                #pragma unroll
                for (int r = 0; r < 4; ++r) aq[rb + g * 4 + r] = c[r] * 128.0f * QSC;
            }
            __syncthreads();
            const size_t rb0 = (size_t)blk * 64;
            #pragma unroll
            for (int it = 0; it < 4; ++it) {
                int idx = threadIdx.x + it * 256;       // 1024 = 64 tok x 16 chunks
                int t = idx >> 4, j = idx & 15;
                h16x8 v = *(const h16x8*)(T + t * 136 + j * 8);
                *(h16x8*)(q + (rb0 + t) * 128 + j * 8) = v;
            }
        } else {
            #pragma unroll
            for (int ct = 0; ct < 8; ++ct)
                #pragma unroll
                for (int r = 0; r < 4; ++r)
                    T[(tok + r) * 136 + ct * 16 + lr] = (_Float16)(acc[ct][r] - c[r]);
            if (lr == 0) {
                #pragma unroll
                for (int r = 0; r < 4; ++r) ck[rb + g * 4 + r] = c[r];
            }
            __syncthreads();
            #pragma unroll
            for (int it = 0; it < 4; ++it) {
                int idx = threadIdx.x + it * 256;       // 64 rows x 16 chunks
                int t = idx >> 4, j = idx & 15;         // t = r64 in tile
                int slot = ((t >> 5) * 2 + ((t >> 2) & 1)) * 16
                         + (((t >> 3) & 3) << 2) + (t & 3);
                h16x8 v = *(const h16x8*)(T + t * 136 + j * 8);
                *(h16x8*)(kimg + ((size_t)blk << 14) + slot * 256
                          + ((j * 16) ^ ((slot & 15) << 4))) = v;
            }
        }
    } else {
        // V: stage TRANSPOSED Tv[e][kv] (stride 72 f16) so image rows are contiguous
        #pragma unroll
        for (int ct = 0; ct < 8; ++ct)
            #pragma unroll
            for (int r = 0; r < 4; ++r)
                T[(ct * 16 + lr) * 72 + tok + r] = (_Float16)acc[ct][r];
        __syncthreads();
        #pragma unroll
        for (int it = 0; it < 4; ++it) {
            int idx = threadIdx.x + it * 256;           // 1024 = 128 e x 8 chunks
            int e = idx >> 3, j = idx & 7;
            h16x8 v = *(const h16x8*)(T + e * 72 + j * 8);
            *(h16x8*)(vimg + ((size_t)blk << 14) + e * 128
                      + ((j * 16) ^ ((e & 7) << 4))) = v;
        }
    }
}

// ---------------- flash attention, split-KV x2, DMA staging (r12 verbatim) ----------------
__global__ __launch_bounds__(256, 2) void flash(const _Float16* __restrict__ q,
                                                const char* __restrict__ kimg,
                                                const char* __restrict__ vimg,
                                                const float* __restrict__ aq,
                                                const float* __restrict__ ck,
                                                float* __restrict__ O0,      // = d_out
                                                float* __restrict__ O1,
                                                float* __restrict__ m0a, float* __restrict__ l0a,
                                                float* __restrict__ m1a, float* __restrict__ l1a) {
    __shared__ __align__(16) char KsB[2][16384];   // 64 slots x 256 B (swizzled image)
    __shared__ __align__(16) char VsB[2][16384];   // 128 rows x 128 B (swizzled image)

    const int bp  = blockIdx.x;
    const int bid = (bp & 7) * 64 + (bp >> 3);

    const int lane = threadIdx.x & 63;
    const int wave = threadIdx.x >> 6;
    const int g    = lane >> 4;
    const int lr   = lane & 15;
    const int b    = bid >> 6;
    const int rem  = bid & 63;
    const int qt   = rem & 31;
    const int half = rem >> 5;
    const int t0   = half * (NT / 2);
    const size_t baseA = (size_t)b * NSEQ + qt * 128 + wave * 32;
    const size_t baseB = baseA + 16;

    float* __restrict__ Opart = half ? O1 : O0;
    float* __restrict__ mArr  = half ? m1a : m0a;
    float* __restrict__ lArr  = half ? l1a : l0a;

    const char* kimg_b = kimg + ((size_t)b << 20);
    const char* vimg_b = vimg + ((size_t)b << 20);
    const float* ckb   = ck + (size_t)b * NSEQ;

    h16x8 qfA[4], qfB[4];
    #pragma unroll
    for (int kc = 0; kc < 4; ++kc) {
        qfA[kc] = *(const h16x8*)(q + (baseA + lr) * 128 + kc * 32 + g * 8);
        qfB[kc] = *(const h16x8*)(q + (baseB + lr) * 128 + kc * 32 + g * 8);
    }
    const float aqvA = aq[baseA + lr];
    const float aqvB = aq[baseB + lr];

    auto stage = [&](int tile, int buf) {
        const char* ks = kimg_b + ((size_t)tile << 14) + wave * 4096 + lane * 16;
        const char* vs = vimg_b + ((size_t)tile << 14) + wave * 4096 + lane * 16;
        char* kd = (char*)KsB[buf] + wave * 4096;
        char* vd = (char*)VsB[buf] + wave * 4096;
        #pragma unroll
        for (int i = 0; i < 4; ++i) {
            __builtin_amdgcn_global_load_lds((guint*)(ks + i * 1024), (luint*)(kd + i * 1024), 16, 0, 0);
            __builtin_amdgcn_global_load_lds((guint*)(vs + i * 1024), (luint*)(vd + i * 1024), 16, 0, 0);
        }
    };

    stage(t0, 0);
    __syncthreads();

    f32x4 oA[8], oB[8];
    #pragma unroll
    for (int ct = 0; ct < 8; ++ct) {
        oA[ct] = (f32x4){0.f, 0.f, 0.f, 0.f};
        oB[ct] = (f32x4){0.f, 0.f, 0.f, 0.f};
    }
    float mA = -1e30f, mB = -1e30f;
    float lA = 0.f, lB = 0.f;

    int cur = 0;
    for (int t = t0; t < t0 + NT / 2; ++t) {
        int tn = (t + 1 < t0 + NT / 2) ? t + 1 : t;
        stage(tn, cur ^ 1);

        f32x4 ckt[4];
        #pragma unroll
        for (int ct = 0; ct < 4; ++ct)
            ckt[ct] = *(const f32x4*)(ckb + t * 64 + (ct >> 1) * 32 + (ct & 1) * 4 + g * 8);

        const char* Kb = KsB[cur];
        f32x4 sA[4], sB[4];
        __builtin_amdgcn_s_setprio(1);
        #pragma unroll
        for (int ct = 0; ct < 4; ++ct) {
            f32x4 aA = (f32x4){0.f, 0.f, 0.f, 0.f};
            f32x4 aB = (f32x4){0.f, 0.f, 0.f, 0.f};
            #pragma unroll
            for (int kc = 0; kc < 4; ++kc) {
                h16x8 kb = *(const h16x8*)(Kb + (ct * 16 + lr) * 256 + ((kc * 64 + g * 16) ^ (lr << 4)));
                aA = __builtin_amdgcn_mfma_f32_16x16x32_f16(kb, qfA[kc], aA, 0, 0, 0);
                aB = __builtin_amdgcn_mfma_f32_16x16x32_f16(kb, qfB[kc], aB, 0, 0, 0);
            }
            #pragma unroll
            for (int r = 0; r < 4; ++r) {
                aA[r] += aqvA * ckt[ct][r];
                aB[r] += aqvB * ckt[ct][r];
            }
            sA[ct] = aA;
            sB[ct] = aB;
        }
        __builtin_amdgcn_s_setprio(0);

        float tmA = sA[0][0], tmB = sB[0][0];
        #pragma unroll
        for (int ct = 0; ct < 4; ++ct)
            #pragma unroll
            for (int r = 0; r < 4; ++r) {
                tmA = fmaxf(tmA, sA[ct][r]);
                tmB = fmaxf(tmB, sB[ct][r]);
            }
        tmA = fmaxf(tmA, __shfl_xor(tmA, 16));
        tmA = fmaxf(tmA, __shfl_xor(tmA, 32));
        tmB = fmaxf(tmB, __shfl_xor(tmB, 16));
        tmB = fmaxf(tmB, __shfl_xor(tmB, 32));
        if (__any((tmA > mA + 11.544f) || (tmB > mB + 11.544f))) {
            float mnA = fmaxf(mA, tmA), mnB = fmaxf(mB, tmB);
            float scA = EXP2(mA - mnA), scB = EXP2(mB - mnB);
            mA = mnA; mB = mnB;
            lA *= scA; lB *= scB;
            float osA[4], osB[4];
            #pragma unroll
            for (int r = 0; r < 4; ++r) {
                osA[r] = __shfl(scA, (lane & 48) | (g * 4 + r));
                osB[r] = __shfl(scB, (lane & 48) | (g * 4 + r));
            }
            #pragma unroll
            for (int ct = 0; ct < 8; ++ct)
                #pragma unroll
                for (int r = 0; r < 4; ++r) {
                    oA[ct][r] *= osA[r];
                    oB[ct][r] *= osB[r];
                }
        }
        #pragma unroll
        for (int ct = 0; ct < 4; ++ct)
            #pragma unroll
            for (int r = 0; r < 4; ++r) {
                float pA = EXP2(sA[ct][r] - mA);
                float pB = EXP2(sB[ct][r] - mB);
                sA[ct][r] = pA; sB[ct][r] = pB;
                lA += pA; lB += pB;
            }

        union Pk { fp16x2 h2[4]; h16x8 v8; };
        h16x8 paA[2], paB[2];
        #pragma unroll
        for (int w = 0; w < 2; ++w) {
            Pk a, bk;
            a.h2[0]  = __builtin_amdgcn_cvt_pkrtz(sA[2 * w][0], sA[2 * w][1]);
            a.h2[1]  = __builtin_amdgcn_cvt_pkrtz(sA[2 * w][2], sA[2 * w][3]);
            a.h2[2]  = __builtin_amdgcn_cvt_pkrtz(sA[2 * w + 1][0], sA[2 * w + 1][1]);
            a.h2[3]  = __builtin_amdgcn_cvt_pkrtz(sA[2 * w + 1][2], sA[2 * w + 1][3]);
            bk.h2[0] = __builtin_amdgcn_cvt_pkrtz(sB[2 * w][0], sB[2 * w][1]);
            bk.h2[1] = __builtin_amdgcn_cvt_pkrtz(sB[2 * w][2], sB[2 * w][3]);
            bk.h2[2] = __builtin_amdgcn_cvt_pkrtz(sB[2 * w + 1][0], sB[2 * w + 1][1]);
            bk.h2[3] = __builtin_amdgcn_cvt_pkrtz(sB[2 * w + 1][2], sB[2 * w + 1][3]);
            paA[w] = a.v8;
            paB[w] = bk.v8;
        }

        const char* Vb = VsB[cur];
        __builtin_amdgcn_s_setprio(1);
        #pragma unroll
        for (int ct = 0; ct < 8; ++ct) {
            #pragma unroll
            for (int w = 0; w < 2; ++w) {
                h16x8 vb = *(const h16x8*)(Vb + (ct * 16 + lr) * 128 + ((w * 64 + g * 16) ^ ((lr & 7) << 4)));
                oA[ct] = __builtin_amdgcn_mfma_f32_16x16x32_f16(paA[w], vb, oA[ct], 0, 0, 0);
                oB[ct] = __builtin_amdgcn_mfma_f32_16x16x32_f16(paB[w], vb, oB[ct], 0, 0, 0);
            }
        }
        __builtin_amdgcn_s_setprio(0);

        __syncthreads();
        cur ^= 1;
    }

    lA += __shfl_xor(lA, 16);
    lA += __shfl_xor(lA, 32);
    lB += __shfl_xor(lB, 16);
    lB += __shfl_xor(lB, 32);
    if (lane < 16) {
        mArr[baseA + lr] = mA;  lArr[baseA + lr] = lA;
        mArr[baseB + lr] = mB;  lArr[baseB + lr] = lB;
    }
    #pragma unroll
    for (int ct = 0; ct < 8; ++ct)
        #pragma unroll
        for (int r = 0; r < 4; ++r) {
            size_t rowA = baseA + g * 4 + r;
            size_t rowB = baseB + g * 4 + r;
            Opart[rowA * EMB + ct * 16 + lr] = oA[ct][r];
            Opart[rowB * EMB + ct * 16 + lr] = oB[ct][r];
        }
}

// ---------------- merge the two kv-halves (r12 verbatim) ----------------
__global__ __launch_bounds__(256) void merge_halves(const float* __restrict__ O1,
                                                    const float* __restrict__ m0a,
                                                    const float* __restrict__ l0a,
                                                    const float* __restrict__ m1a,
                                                    const float* __restrict__ l1a,
                                                    float* __restrict__ out) {
    int gid = blockIdx.x * 256 + threadIdx.x;    // 32768 rows x 16 threads
    int row = gid >> 4;
    int c0  = (gid & 15) * 8;
    float mm0 = m0a[row], mm1 = m1a[row];
    float M   = fmaxf(mm0, mm1);
    float w0  = EXP2(mm0 - M), w1 = EXP2(mm1 - M);
    float inv = 1.0f / (l0a[row] * w0 + l1a[row] * w1);
    float*       p0 = out + (size_t)row * EMB + c0;
    const float* p1 = O1  + (size_t)row * EMB + c0;
    f32x4 a0 = *(const f32x4*)p0, a1 = *(const f32x4*)(p0 + 4);
    f32x4 b0 = *(const f32x4*)p1, b1 = *(const f32x4*)(p1 + 4);
    f32x4 r0 = (a0 * w0 + b0 * w1) * inv;
    f32x4 r1 = (a1 * w0 + b1 * w1) * inv;
    *(f32x4*)p0       = r0;
    *(f32x4*)(p0 + 4) = r1;
}

extern "C" void kernel_launch(void* const* d_in, const int* in_sizes, int n_in,
                              void* d_out, int out_size, void* d_ws, size_t ws_size,
                              hipStream_t stream) {
    const float* x  = (const float*)d_in[0];
    const float* wq = (const float*)d_in[1];
    const float* wk = (const float*)d_in[2];
    const float* wv = (const float*)d_in[3];

    char* ws = (char*)d_ws;
    _Float16* q    = (_Float16*)(ws);                          // 8 MB
    char*     kimg = (char*)    (ws + 8388608);                // 8 MB (tile images)
    char*     vimg = (char*)    (ws + 16777216);               // 8 MB (tile images)
    float*    aq   = (float*)   (ws + 25165824);               // 128 KB
    float*    ck   = (float*)   (ws + 25296896);               // 128 KB
    _Float16* whiT = (_Float16*)(ws + 25427968);               // 96 KB
    _Float16* wloT = (_Float16*)(ws + 25526272);               // 96 KB
    float*    O1   = (float*)   (ws + 25690112);               // 16 MB
    float*    m0a  = (float*)   (ws + 42467328);               // 128 KB
    float*    l0a  = (float*)   (ws + 42598400);               // 128 KB
    float*    m1a  = (float*)   (ws + 42729472);               // 128 KB
    float*    l1a  = (float*)   (ws + 42860544);               // 128 KB

    prep_w<<<192, 256, 0, stream>>>(wq, wk, wv, whiT, wloT);
    qkv_proj<<<1536, 256, 0, stream>>>(x, whiT, wloT, q, kimg, vimg, aq, ck);
    flash<<<512, 256, 0, stream>>>(q, kimg, vimg, aq, ck,
                                   (float*)d_out, O1, m0a, l0a, m1a, l1a);
    merge_halves<<<2048, 256, 0, stream>>>(O1, m0a, l0a, m1a, l1a, (float*)d_out);
}